// Round 5
// baseline (1748.690 us; speedup 1.0000x reference)
//
#include <hip/hip_runtime.h>

// RNN B=256 T=2048 I=64 H=256 — STAGGERED PAIR: 2 samples per 512-thr WG
// (grid=128). Waves 0-3 = sample A, 4-7 = sample B (1 A + 1 B per SIMD).
// Measured TLP curve (R2/R1/R4: 1195/982/1150 us at 1/2/4 waves-per-SIMD)
// shows a lockstep serial chain is ~60% stall (MfmaUtil 24 + VALUBusy 17);
// symmetric waves stall together. Fix: half-step phase stagger with 2
// barriers/step — while A does {ds_read h + MFMA chain}, B does
// {extract+tanh+write}, then swap. Both samples advance 1 step / 2 phases;
// per-sample step time ~ the LOAD phase, not LOAD+FINISH serial.
//  - per group: R2 structure (wave owns 64 rows; Ah[4][8]; 8 partials,
//    chain depth 4; every lane owns exactly one output row).
//  - xp precomputed per 32-step block (mini-GEMM, timesteps as MFMA cols),
//    stored f16 (LDS budget), read into a register at LOAD time so the next
//    block's mini-GEMM can't clobber it (B finishes step 31 after it).
//  - samples freeze past their own len via gated h-writes; WG runs max len.
// Falsification pre-commit: >=1000us => barrier-cost-dominated.

static constexpr int nB = 256;
static constexpr int nT = 2048;
static constexpr int nI = 64;
static constexpr int nH = 256;
static constexpr int XBLK = 32;     // timesteps of x staged/projected per block
static constexpr int XSTR = 72;     // halfword stride of an xbuf row
static constexpr int XPS  = 34;     // halfword stride of an xp row (odd pairs -> spread banks)
static constexpr int THREADS = 512; // 8 waves: 2 groups x 4 waves

typedef _Float16 f16x8 __attribute__((ext_vector_type(8)));
typedef _Float16 f16x4 __attribute__((ext_vector_type(4)));
typedef float f32x4 __attribute__((ext_vector_type(4)));

__device__ __forceinline__ float fast_tanh(float x) {
  float a = fabsf(x);
  float e = __expf(-2.0f * a);           // in (0,1], never overflows
  float r = (1.0f - e) * __builtin_amdgcn_rcpf(1.0f + e);
  return copysignf(r, x);
}

__global__ __launch_bounds__(THREADS, 2)
void rnn_mfma(const float* __restrict__ x, const int* __restrict__ lengths,
              const float* __restrict__ Wih, const float* __restrict__ Whh,
              const float* __restrict__ bih, const float* __restrict__ bhh,
              const float* __restrict__ Wfc, const float* __restrict__ bfc,
              float* __restrict__ out)
{
  __shared__ __align__(16) _Float16 hbuf[2][2][nH];           // [group][parity] 2 KB
  __shared__ __align__(16) _Float16 xbuf[2][2][XBLK * XSTR];  // [group][parity] 18.4 KB
  __shared__ __align__(16) _Float16 xpf[2][nH * XPS];         // [group] f16 xp, 34.8 KB
  __shared__ float red[8];

  const int tid  = threadIdx.x;
  const int g    = tid >> 8;      // 0 = sample A, 1 = sample B
  const int gtid = tid & 255;
  const int wg   = gtid >> 6;     // wave within group 0..3
  const int l    = tid & 63;
  const int q    = l >> 4;        // quad 0..3
  const int n    = l & 15;        // MFMA column lane

  const int lenA = lengths[2 * blockIdx.x];
  const int lenB = lengths[2 * blockIdx.x + 1];
  const int mylen  = g ? lenB : lenA;
  const int maxlen = max(lenA, lenB);
  const int sample = 2 * blockIdx.x + g;
  const float* xb = x + (size_t)sample * nT * nI;

  // ---- pack this wave's 64 W rows into A-fragments (f16); same for both groups
  // A layout (16x16x32): lane holds A[m = lane&15][k = 8*(lane>>4) + j]
  f16x8 Ah[4][8];   // W_hh rows 64wg+16mt+n, k = 32kt+8q+j
  f16x8 Ax[4][2];   // W_ih (I=64 -> 2 k-tiles), mini-GEMM only
#pragma unroll
  for (int mt = 0; mt < 4; ++mt) {
    const int row = 64 * wg + 16 * mt + n;
#pragma unroll
    for (int kt = 0; kt < 8; ++kt) {
      const float* src = Whh + row * nH + 32 * kt + 8 * q;
      f16x8 a;
#pragma unroll
      for (int j = 0; j < 8; ++j) a[j] = (_Float16)src[j];
      Ah[mt][kt] = a;
    }
#pragma unroll
    for (int kt = 0; kt < 2; ++kt) {
      const float* src = Wih + row * nI + 32 * kt + 8 * q;
      f16x8 a;
#pragma unroll
      for (int j = 0; j < 8; ++j) a[j] = (_Float16)src[j];
      Ax[mt][kt] = a;
    }
  }
  f32x4 biasC[4];
#pragma unroll
  for (int mt = 0; mt < 4; ++mt)
#pragma unroll
    for (int r = 0; r < 4; ++r) {
      const int r0 = 64 * wg + 16 * mt + 4 * q + r;
      biasC[mt][r] = bih[r0] + bhh[r0];
    }
  const int mt_sel  = n >> 2;
  const int reg_sel = n & 3;
  const int row_own = 64 * wg + 16 * mt_sel + 4 * q + reg_sel;

  // x staging: 256 thr/group x 2 float4 = 2048 floats = one 32-step block
  const int offA = gtid * 4;
  const int offB = offA + 1024;
  const int dstA = (offA >> 6) * XSTR + (offA & 63);
  const int dstB = (offB >> 6) * XSTR + (offB & 63);

  // ---- h0 = 0; stage x block 0 (per group)
  hbuf[g][0][gtid] = (_Float16)0.f;
  {
    float4 vA = *(const float4*)(xb + offA);
    float4 vB = *(const float4*)(xb + offB);
    f16x4 pA = { (_Float16)vA.x, (_Float16)vA.y, (_Float16)vA.z, (_Float16)vA.w };
    f16x4 pB = { (_Float16)vB.x, (_Float16)vB.y, (_Float16)vB.z, (_Float16)vB.w };
    *(f16x4*)(xbuf[g][0] + dstA) = pA;
    *(f16x4*)(xbuf[g][0] + dstB) = pB;
  }
  __syncthreads();

  // cross-phase persistent state
  f32x4 pe[4], po[4];
  float xpv = 0.f;
  float4 preA, preB;

  for (int blk = 0; blk * XBLK < maxlen; ++blk) {
    const int t0 = blk * XBLK;
    const int nsteps = min(XBLK, maxlen - t0);
    const bool havepre = ((blk + 1) * XBLK < maxlen);

    // ---- mini-GEMM phase: xp[row][s] = bias + W_ih . x_{t0+s} (per group)
    {
      const _Float16* xB = xbuf[g][blk & 1];
      f32x4 g0[4], g1[4];
#pragma unroll
      for (int mt = 0; mt < 4; ++mt) { g0[mt] = biasC[mt]; g1[mt] = biasC[mt]; }
#pragma unroll
      for (int kt = 0; kt < 2; ++kt) {
        f16x8 B0 = *(const f16x8*)(xB + n * XSTR + 32 * kt + 8 * q);         // s = n
        f16x8 B1 = *(const f16x8*)(xB + (16 + n) * XSTR + 32 * kt + 8 * q);  // s = 16+n
#pragma unroll
        for (int mt = 0; mt < 4; ++mt) {
          g0[mt] = __builtin_amdgcn_mfma_f32_16x16x32_f16(Ax[mt][kt], B0, g0[mt], 0, 0, 0);
          g1[mt] = __builtin_amdgcn_mfma_f32_16x16x32_f16(Ax[mt][kt], B1, g1[mt], 0, 0, 0);
        }
      }
#pragma unroll
      for (int mt = 0; mt < 4; ++mt)
#pragma unroll
        for (int r = 0; r < 4; ++r) {
          const int r0 = 64 * wg + 16 * mt + 4 * q + r;
          xpf[g][r0 * XPS + n]      = (_Float16)g0[mt][r];
          xpf[g][r0 * XPS + 16 + n] = (_Float16)g1[mt][r];
        }
    }
    __syncthreads();

    // LOAD: read xpv + h(t), run 32-MFMA chain into pe/po (regs persist
    // across the phase barrier). FINISH: extract, tanh, gated h-write.
    auto LOAD = [&](const _Float16* hsrc, int s) {
      xpv = (float)xpf[g][row_own * XPS + s];
      f32x4 z = {0.f, 0.f, 0.f, 0.f};
#pragma unroll
      for (int mt = 0; mt < 4; ++mt) { pe[mt] = z; po[mt] = z; }
#pragma unroll
      for (int i = 0; i < 4; ++i) {
        f16x8 Ba = *(const f16x8*)(hsrc + 64 * i + 8 * q);
        f16x8 Bb = *(const f16x8*)(hsrc + 64 * i + 32 + 8 * q);
#pragma unroll
        for (int mt = 0; mt < 4; ++mt) {
          pe[mt] = __builtin_amdgcn_mfma_f32_16x16x32_f16(Ah[mt][2 * i],     Ba, pe[mt], 0, 0, 0);
          po[mt] = __builtin_amdgcn_mfma_f32_16x16x32_f16(Ah[mt][2 * i + 1], Bb, po[mt], 0, 0, 0);
        }
      }
    };
    auto FINISH = [&](int t, _Float16* hdst, bool wb) {
      f32x4 s0 = pe[0] + po[0], s1 = pe[1] + po[1];
      f32x4 s2 = pe[2] + po[2], s3 = pe[3] + po[3];
      f32x4 ma = (mt_sel & 1) ? s1 : s0;
      f32x4 mb = (mt_sel & 1) ? s3 : s2;
      f32x4 c  = (mt_sel & 2) ? mb : ma;
      float lo = (reg_sel & 1) ? c[1] : c[0];
      float hi = (reg_sel & 1) ? c[3] : c[2];
      float v  = ((reg_sel & 2) ? hi : lo) + xpv;
      float hn = fast_tanh(v);
      if (wb) {  // stage next x block before the phase barrier
        f16x4 pA = { (_Float16)preA.x, (_Float16)preA.y, (_Float16)preA.z, (_Float16)preA.w };
        f16x4 pB = { (_Float16)preB.x, (_Float16)preB.y, (_Float16)preB.z, (_Float16)preB.w };
        _Float16* d = xbuf[g][(blk + 1) & 1];
        *(f16x4*)(d + dstA) = pA;
        *(f16x4*)(d + dstB) = pB;
      }
      if (t < mylen) hdst[row_own] = (_Float16)hn;
    };

    for (int s = 0; s < nsteps; ++s) {
      const int t = t0 + s;
      const int p = s & 1;            // == t&1 (t0 is a multiple of 32)
      const _Float16* hsrc = hbuf[g][p];
      // issue next-block x prefetch after the mini-GEMM barrier (s==0 only)
      if (s == 0 && havepre) {
        const float* nx = xb + (size_t)(blk + 1) * XBLK * nI;
        preA = *(const float4*)(nx + offA);
        preB = *(const float4*)(nx + offB);
      }
      // ---- P0: A loads+MFMAs step t; B finishes step t-1 (writes h_t)
      if (g == 0)      LOAD(hsrc, s);
      else if (t > 0)  FINISH(t - 1, hbuf[1][p], false);
      __syncthreads();
      // ---- P1: A finishes step t (writes h_{t+1}); B loads+MFMAs step t
      if (g == 0) {
        FINISH(t, hbuf[0][p ^ 1], (s == nsteps - 1) && havepre);
      } else {
        LOAD(hsrc, s);
        if (s == nsteps - 1 && havepre) {
          f16x4 pA = { (_Float16)preA.x, (_Float16)preA.y, (_Float16)preA.z, (_Float16)preA.w };
          f16x4 pB = { (_Float16)preB.x, (_Float16)preB.y, (_Float16)preB.z, (_Float16)preB.w };
          _Float16* d = xbuf[1][(blk + 1) & 1];
          *(f16x4*)(d + dstA) = pA;
          *(f16x4*)(d + dstB) = pB;
        }
      }
      __syncthreads();
    }
  }

  // ---- B still owes the finish of its last step (half-step behind)
  if (g == 1) {
    f32x4 s0 = pe[0] + po[0], s1 = pe[1] + po[1];
    f32x4 s2 = pe[2] + po[2], s3 = pe[3] + po[3];
    f32x4 ma = (mt_sel & 1) ? s1 : s0;
    f32x4 mb = (mt_sel & 1) ? s3 : s2;
    f32x4 c  = (mt_sel & 2) ? mb : ma;
    float lo = (reg_sel & 1) ? c[1] : c[0];
    float hi = (reg_sel & 1) ? c[3] : c[2];
    float v  = ((reg_sel & 2) ? hi : lo) + xpv;
    float hn = fast_tanh(v);
    if (maxlen - 1 < mylen) hbuf[1][maxlen & 1][row_own] = (_Float16)hn;
  }
  __syncthreads();

  // ---- epilogue: out[sample] = h_final . W_fc + b_fc (per group)
  float v = (float)hbuf[g][mylen & 1][gtid] * Wfc[gtid];
#pragma unroll
  for (int off = 32; off; off >>= 1) v += __shfl_down(v, off);
  if (l == 0) red[tid >> 6] = v;
  __syncthreads();
  if (gtid == 0) {
    float acc = bfc[0];
#pragma unroll
    for (int i = 0; i < 4; ++i) acc += red[4 * g + i];
    out[sample] = acc;
  }
}

extern "C" void kernel_launch(void* const* d_in, const int* in_sizes, int n_in,
                              void* d_out, int out_size, void* d_ws, size_t ws_size,
                              hipStream_t stream) {
  const float* x   = (const float*)d_in[0];
  const int* lens  = (const int*)d_in[1];
  const float* Wih = (const float*)d_in[2];
  const float* Whh = (const float*)d_in[3];
  const float* bih = (const float*)d_in[4];
  const float* bhh = (const float*)d_in[5];
  const float* Wfc = (const float*)d_in[6];
  const float* bfc = (const float*)d_in[7];
  float* out = (float*)d_out;

  rnn_mfma<<<nB / 2, THREADS, 0, stream>>>(x, lens, Wih, Whh, bih, bhh, Wfc, bfc, out);
}

// Round 6
// 983.611 us; speedup vs baseline: 1.7778x; 1.7778x over previous
//
#include <hip/hip_runtime.h>

// RNN B=256 T=2048 I=64 H=256 — one workgroup per sample, MFMA matvec recurrence.
// Wall = max len (2048) x per-step critical path; R1's 8-wave/2-per-SIMD lockstep
// (982us, 1150cy/step) is the TLP optimum (measured U: 1195/982/1150 at 1/2/4
// waves-per-SIMD; R5's staggered pair spilled to scratch, 1698us).
// R6 strips per-step overhead from the R1 step (serial-path VALU/LDS ops):
//  - hot 32-step block FULLY UNROLLED: compile-time s -> ds_read base+imm
//    offsets, static hbuf parity, writeback branch folds into copy 31.
//  - lane's xp row preloaded to 8 f32x4 regs per block (static index in the
//    unrolled body); xp stride 36 floats (16B-aligned rows, 2-way banks max).
//  - setprio dropped (R3: pure overhead in lockstep). Kept: prefetch issued
//    after mini-GEMM barrier, rcp-tanh, f32 xp, kt-parity depth-4 chains.
// Spill canary: WRITE_SIZE must stay ~11KB (R5's 7.4MB = scratch).

static constexpr int nB = 256;
static constexpr int nT = 2048;
static constexpr int nI = 64;
static constexpr int nH = 256;
static constexpr int XBLK = 32;     // timesteps of x staged/projected per block
static constexpr int XSTR = 72;     // halfword stride of an xbuf row
static constexpr int XPS  = 36;     // float stride of an xp row (144B: 16B-aligned)
static constexpr int THREADS = 512; // 8 waves; wave w owns output rows [32w,32w+32)

typedef _Float16 f16x8 __attribute__((ext_vector_type(8)));
typedef _Float16 f16x4 __attribute__((ext_vector_type(4)));
typedef float f32x4 __attribute__((ext_vector_type(4)));

__device__ __forceinline__ float fast_tanh(float x) {
  float a = fabsf(x);
  float e = __expf(-2.0f * a);           // in (0,1], never overflows
  float r = (1.0f - e) * __builtin_amdgcn_rcpf(1.0f + e);
  return copysignf(r, x);
}

__global__ __launch_bounds__(THREADS, 2)
void rnn_mfma(const float* __restrict__ x, const int* __restrict__ lengths,
              const float* __restrict__ Wih, const float* __restrict__ Whh,
              const float* __restrict__ bih, const float* __restrict__ bhh,
              const float* __restrict__ Wfc, const float* __restrict__ bfc,
              float* __restrict__ out)
{
  __shared__ __align__(16) _Float16 hbuf[2][nH];            // 1 KB
  __shared__ __align__(16) _Float16 xbuf[2][XBLK * XSTR];   // 9 KB
  __shared__ __align__(16) float xp[nH * XPS];              // 36 KB
  __shared__ float red[THREADS / 64];

  const int b   = blockIdx.x;
  const int tid = threadIdx.x;
  const int w   = tid >> 6;       // wave 0..7
  const int l   = tid & 63;
  const int q   = l >> 4;         // quad 0..3
  const int n   = l & 15;         // MFMA column lane
  const int len = lengths[b];     // in [1, nT]
  const float* xb = x + (size_t)b * nT * nI;

  // ---- preamble: pack this wave's W rows into A-fragments (f16)
  // A layout (16x16x32): lane holds A[m = lane&15][k = 8*(lane>>4) + j], j=0..7
  f16x8 Ah[2][8];   // W_hh rows 32w+16mt+n, k = 32kt+8q+j
  f16x8 Ax[2][2];   // W_ih (I=64 -> 2 k-tiles), mini-GEMM only
#pragma unroll
  for (int mt = 0; mt < 2; ++mt) {
    const int row = 32 * w + 16 * mt + n;
#pragma unroll
    for (int kt = 0; kt < 8; ++kt) {
      const float* src = Whh + row * nH + 32 * kt + 8 * q;
      f16x8 a;
#pragma unroll
      for (int j = 0; j < 8; ++j) a[j] = (_Float16)src[j];
      Ah[mt][kt] = a;
    }
#pragma unroll
    for (int kt = 0; kt < 2; ++kt) {
      const float* src = Wih + row * nI + 32 * kt + 8 * q;
      f16x8 a;
#pragma unroll
      for (int j = 0; j < 8; ++j) a[j] = (_Float16)src[j];
      Ax[mt][kt] = a;
    }
  }
  // bias in C layout: reg r <-> row 32w + 16mt + 4q + r (folded into xp)
  f32x4 biasC[2];
#pragma unroll
  for (int r = 0; r < 4; ++r) {
    const int r0 = 32 * w + 4 * q + r;
    biasC[0][r] = bih[r0] + bhh[r0];
    biasC[1][r] = bih[r0 + 16] + bhh[r0 + 16];
  }
  // column-split ownership: lanes n<8 each finish exactly one output row
  const int mt_sel  = (n >> 2) & 1;
  const int reg_sel = n & 3;
  const int row_own = 32 * w + 16 * mt_sel + 4 * q + reg_sel;

  // x staging geometry: thread writes 4 halfs at (row, col) of the block
  const int xoff = ((tid * 4) >> 6) * XSTR + ((tid * 4) & 63);

  // ---- h0 = 0; stage x block 0
  if (tid < nH) hbuf[0][tid] = (_Float16)0.f;
  {
    float4 v = *(const float4*)(xb + tid * 4);
    f16x4 pv = { (_Float16)v.x, (_Float16)v.y, (_Float16)v.z, (_Float16)v.w };
    *(f16x4*)(xbuf[0] + xoff) = pv;
  }
  __syncthreads();

  int t = 0;
  for (int blk = 0; t < len; ++blk) {
    // ---- xp mini-GEMM: xp[row][s] = bias + W_ih . x_{blk*32+s}; timesteps
    // are the MFMA columns (ct=0 -> s=n, ct=1 -> s=16+n).
    {
      const _Float16* xB = xbuf[blk & 1];
      f32x4 g00 = biasC[0], g01 = biasC[0], g10 = biasC[1], g11 = biasC[1];
#pragma unroll
      for (int kt = 0; kt < 2; ++kt) {
        f16x8 B0 = *(const f16x8*)(xB + n * XSTR + 32 * kt + 8 * q);         // ct=0
        f16x8 B1 = *(const f16x8*)(xB + (16 + n) * XSTR + 32 * kt + 8 * q);  // ct=1
        g00 = __builtin_amdgcn_mfma_f32_16x16x32_f16(Ax[0][kt], B0, g00, 0, 0, 0);
        g10 = __builtin_amdgcn_mfma_f32_16x16x32_f16(Ax[1][kt], B0, g10, 0, 0, 0);
        g01 = __builtin_amdgcn_mfma_f32_16x16x32_f16(Ax[0][kt], B1, g01, 0, 0, 0);
        g11 = __builtin_amdgcn_mfma_f32_16x16x32_f16(Ax[1][kt], B1, g11, 0, 0, 0);
      }
#pragma unroll
      for (int r = 0; r < 4; ++r) {
        const int r0 = (32 * w + 4 * q + r) * XPS;
        xp[r0 + n]              = g00[r];
        xp[r0 + 16 * XPS + n]   = g10[r];
        xp[r0 + 16 + n]         = g01[r];
        xp[r0 + 16 * XPS + 16 + n] = g01[r], xp[r0 + 16 * XPS + 16 + n] = g11[r];
      }
    }
    __syncthreads();

    // next-block x prefetch AFTER the barrier (first vmcnt(0) drain is a full
    // step later -> HBM latency hidden), then this lane's xp row -> registers.
    float4 pre;
    const bool havepre = ((blk + 1) * XBLK < len);
    if (havepre)
      pre = *(const float4*)(xb + (size_t)(blk + 1) * XBLK * nI + tid * 4);

    f32x4 xr[8];
#pragma unroll
    for (int k = 0; k < 8; ++k)
      xr[k] = *(const f32x4*)(xp + row_own * XPS + 4 * k);

    const int nsteps = min(XBLK, len - blk * XBLK);

    // step body; xpv passed in (reg in hot path, LDS read in tail)
    auto step = [&](float xpv, const _Float16* hsrc, _Float16* hdst, bool wb) {
      f32x4 z = {0.f, 0.f, 0.f, 0.f};
      f32x4 p00 = z, p01 = z, p10 = z, p11 = z;  // kt-parity partials: depth 4
#pragma unroll
      for (int kt = 0; kt < 8; kt += 2) {
        f16x8 Be = *(const f16x8*)(hsrc + 32 * kt + 8 * q);
        f16x8 Bo = *(const f16x8*)(hsrc + 32 * (kt + 1) + 8 * q);
        p00 = __builtin_amdgcn_mfma_f32_16x16x32_f16(Ah[0][kt],     Be, p00, 0, 0, 0);
        p10 = __builtin_amdgcn_mfma_f32_16x16x32_f16(Ah[1][kt],     Be, p10, 0, 0, 0);
        p01 = __builtin_amdgcn_mfma_f32_16x16x32_f16(Ah[0][kt + 1], Bo, p01, 0, 0, 0);
        p11 = __builtin_amdgcn_mfma_f32_16x16x32_f16(Ah[1][kt + 1], Bo, p11, 0, 0, 0);
      }
      f32x4 s0 = p00 + p01;
      f32x4 s1 = p10 + p11;
      float lo0 = (reg_sel & 1) ? s0[1] : s0[0];
      float hi0 = (reg_sel & 1) ? s0[3] : s0[2];
      float v0  = (reg_sel & 2) ? hi0 : lo0;
      float lo1 = (reg_sel & 1) ? s1[1] : s1[0];
      float hi1 = (reg_sel & 1) ? s1[3] : s1[2];
      float v1  = (reg_sel & 2) ? hi1 : lo1;
      float v   = (mt_sel ? v1 : v0) + xpv;
      float hn  = fast_tanh(v);
      if (wb) {  // stage next x block before this block's final barrier
        f16x4 pv = { (_Float16)pre.x, (_Float16)pre.y, (_Float16)pre.z, (_Float16)pre.w };
        *(f16x4*)(xbuf[(blk + 1) & 1] + xoff) = pv;
      }
      if (n < 8) hdst[row_own] = (_Float16)hn;
      __syncthreads();
    };

    if (nsteps == XBLK) {
      // ---- hot path: fully unrolled, everything compile-time
#pragma unroll
      for (int s = 0; s < XBLK; ++s)
        step(xr[s >> 2][s & 3], hbuf[s & 1], hbuf[(s + 1) & 1],
             (s == XBLK - 1) && havepre);
    } else {
      // ---- tail (last block of this sample): dynamic, xp from LDS
      for (int s = 0; s < nsteps; ++s)
        step(xp[row_own * XPS + s], hbuf[s & 1], hbuf[(s + 1) & 1], false);
    }
    t += nsteps;
  }

  // ---- epilogue: out[b] = h_final . W_fc + b_fc
  float v = 0.f;
  if (tid < nH) v = (float)hbuf[len & 1][tid] * Wfc[tid];
#pragma unroll
  for (int off = 32; off; off >>= 1) v += __shfl_down(v, off);
  if (l == 0) red[w] = v;
  __syncthreads();
  if (tid == 0) {
    float acc = bfc[0];
#pragma unroll
    for (int i = 0; i < THREADS / 64; ++i) acc += red[i];
    out[b] = acc;
  }
}

extern "C" void kernel_launch(void* const* d_in, const int* in_sizes, int n_in,
                              void* d_out, int out_size, void* d_ws, size_t ws_size,
                              hipStream_t stream) {
  const float* x   = (const float*)d_in[0];
  const int* lens  = (const int*)d_in[1];
  const float* Wih = (const float*)d_in[2];
  const float* Whh = (const float*)d_in[3];
  const float* bih = (const float*)d_in[4];
  const float* bhh = (const float*)d_in[5];
  const float* Wfc = (const float*)d_in[6];
  const float* bfc = (const float*)d_in[7];
  float* out = (float*)d_out;

  rnn_mfma<<<nB, THREADS, 0, stream>>>(x, lens, Wih, Whh, bih, bhh, Wfc, bfc, out);
}